// Round 13
// baseline (737.852 us; speedup 1.0000x reference)
//
#include <hip/hip_runtime.h>

#define N_NODES 100000
#define N_EDGES 1600000
#define HID 128
#define SCAN_N (N_NODES*4)
#define NB1 ((SCAN_N + 1023) / 1024)
#define ZERO_IDX (N_NODES*4)   // gather index of the zero pad row in Y

#define EB 8192                // edges per block in bucket pipeline
#define NBLKA ((N_EDGES + EB - 1) / EB)          // 196
#define BSH 9                  // 512 nodes per bucket
#define NBUCK ((N_NODES + (1<<BSH) - 1) >> BSH)  // 196
#define N2 (NBUCK * NBLKA)
#define NB2 ((N2 + 1023) / 1024)

typedef __attribute__((ext_vector_type(8))) short short8;
typedef __attribute__((ext_vector_type(4))) float float4v;
typedef __attribute__((ext_vector_type(4))) int int4v;
typedef __attribute__((ext_vector_type(4))) unsigned int uint4v;
typedef __attribute__((ext_vector_type(2))) unsigned int uint2v;
typedef unsigned short ushort_t;
typedef unsigned int uint_t;

__device__ __forceinline__ float bits2f(uint_t u){ union{uint_t u; float f;} x; x.u=u; return x.f; }
__device__ __forceinline__ float b2f(ushort_t u){ return bits2f(((uint_t)u)<<16); }
__device__ __forceinline__ ushort_t f2b(float f){
  union{float f; uint_t u;} x; x.f=f;
  uint_t r = x.u + 0x7fffu + ((x.u>>16)&1u);
  return (ushort_t)(r>>16);
}
// packed f32x2 -> bf16x2 (RNE), single instruction
__device__ __forceinline__ uint_t cvtpk(float a, float b){
  uint_t r; asm("v_cvt_pk_bf16_f32 %0, %1, %2" : "=v"(r) : "v"(a), "v"(b)); return r;
}
__device__ __forceinline__ float fsigm(float x){ return __builtin_amdgcn_rcpf(1.0f + __expf(-x)); }
__device__ __forceinline__ float ftanh(float x){ return 2.0f*__builtin_amdgcn_rcpf(1.0f + __expf(-2.0f*x)) - 1.0f; }
__device__ __forceinline__ int imin(int a, int b){ return a < b ? a : b; }
// K-space permutation: stored p = pi(c) = (c&15)*8 + (c>>4); pinv = inverse
__device__ __forceinline__ int pinv(int p){ return ((p&7)<<4) | (p>>3); }

// ---------------- preprocessing ----------------

// All weight K/d indices prepacked with pi applied (storage permutation of the 128-dim).
// WY[g][p] = W_edge[g][pinv(p)], row-major [512][128]  (one-shot transform)
// W2f fragment-major GRU weights, K stored-permuted per 128-half.
// WYf fragment-major W_edge for phase 2, K stored-permuted.
// bEp[t*128+p] = b_edge[t*128+pinv(p)].
__global__ void prep_weights(const float* __restrict__ W_edge, const float* __restrict__ W_ih,
                             const float* __restrict__ W_hh, const float* __restrict__ b_edge,
                             ushort_t* __restrict__ WY, ushort_t* __restrict__ W2f,
                             ushort_t* __restrict__ WYf, float* __restrict__ bEp){
  int i = blockIdx.x*256 + threadIdx.x;
  if (i < 65536){
    int g = i >> 7, p = i & 127;
    WY[i] = f2b(W_edge[g*128 + pinv(p)]);
  } else if (i < 65536 + 131072){
    int i2 = i - 65536;
    int tile = i2 >> 9, e9 = i2 & 511;
    int lane = e9 >> 3, e = e9 & 7;
    int kk = tile & 1, kt = (tile >> 1) & 3, j = (tile >> 3) & 7, wn = tile >> 6;
    int lq = lane >> 4, l15 = lane & 15;
    int c = wn*32 + (j&1)*16 + l15;
    int jg = j >> 1;
    int k = kt*64 + (kk*4 + lq)*8 + e;   // stored K in [0,256)
    int d = pinv(k & 127);               // orig d within the half
    bool aside = (k < 128);
    float v;
    if (jg < 2)       v = aside ? W_ih[(jg*128 + c)*128 + d] : W_hh[(jg*128 + c)*128 + d];
    else if (jg == 2) v = aside ? W_ih[(256 + c)*128 + d] : 0.0f;
    else              v = aside ? 0.0f : W_hh[(256 + c)*128 + d];
    W2f[i2] = f2b(v);
  } else if (i < 65536 + 131072 + 65536){
    int i3 = i - 65536 - 131072;
    int tile = i3 >> 9, e9 = i3 & 511;
    int lane = e9 >> 3, e = e9 & 7;
    int kc = tile & 3, j = (tile >> 2) & 7, wn = tile >> 5;
    int lq = lane >> 4, l15 = lane & 15;
    int n = wn*128 + j*16 + l15;
    int k = kc*32 + lq*8 + e;
    WYf[i3] = f2b(W_edge[n*128 + pinv(k)]);
  } else if (i < 65536 + 131072 + 65536 + 512){
    int i4 = i - 65536 - 131072 - 65536;
    int t = i4 >> 7, p = i4 & 127;
    bEp[i4] = b_edge[t*128 + pinv(p)];
  }
}

// etype argmax, pack (src<<2)|t, histogram cnt[dst*4+t] and per-block bucket hist
__global__ void edge_pass1(const int* __restrict__ eidx, const float* __restrict__ efeat,
                           int* __restrict__ packed, int* __restrict__ cnt,
                           int* __restrict__ bcntT){
  __shared__ int hist[NBUCK];
  int tid = threadIdx.x, blk = blockIdx.x;
  for (int j = tid; j < NBUCK; j += 512) hist[j] = 0;
  __syncthreads();
  #pragma unroll
  for (int k = 0; k < EB/512; ++k){
    int e = blk*EB + k*512 + tid;
    if (e < N_EDGES){
      int src = eidx[e], dst = eidx[N_EDGES + e];
      float4v f = *(const float4v*)(efeat + (size_t)e*4);
      int t = 0; float b = f[0];
      if (f[1] > b){ b = f[1]; t = 1; }
      if (f[2] > b){ b = f[2]; t = 2; }
      if (f[3] > b){ b = f[3]; t = 3; }
      packed[e] = (src << 2) | t;
      atomicAdd(&cnt[dst*4 + t], 1);
      atomicAdd(&hist[dst >> BSH], 1);
    }
  }
  __syncthreads();
  for (int j = tid; j < NBUCK; j += 512) bcntT[j*NBLKA + blk] = hist[j];
}

// generalized 3-pass exclusive scan (n elements)
__global__ void scan_pass1(const int* __restrict__ src, int* __restrict__ bsum, int n){
  __shared__ int ws[4];
  int tid = threadIdx.x, lane = tid & 63, w = tid >> 6;
  int idx = blockIdx.x*1024 + tid*4;
  int v = 0;
  if (idx + 3 < n){ int4v x = *(const int4v*)(src + idx); v = x[0]+x[1]+x[2]+x[3]; }
  else { for (int k = 0; k < 4; ++k) if (idx + k < n) v += src[idx+k]; }
  for (int d = 32; d; d >>= 1) v += __shfl_down(v, d);
  if (lane == 0) ws[w] = v;
  __syncthreads();
  if (tid == 0) bsum[blockIdx.x] = ws[0]+ws[1]+ws[2]+ws[3];
}

__global__ void scan_pass2(const int* __restrict__ bsum, int* __restrict__ bpre,
                           int* __restrict__ total_out, int nb){
  __shared__ int sh[512];
  int tid = threadIdx.x;
  int v = (tid < nb) ? bsum[tid] : 0;
  sh[tid] = v;
  __syncthreads();
  for (int d = 1; d < 512; d <<= 1){
    int y = (tid >= d) ? sh[tid-d] : 0;
    __syncthreads();
    sh[tid] += y;
    __syncthreads();
  }
  if (tid < nb) bpre[tid] = sh[tid] - v;
  if (tid == 511) *total_out = sh[511];
}

__global__ void scan_pass3(const int* __restrict__ src, const int* __restrict__ bpre,
                           int* __restrict__ off, int n){
  __shared__ int wsum[4];
  int tid = threadIdx.x, lane = tid & 63, w = tid >> 6;
  int idx = blockIdx.x*1024 + tid*4;
  int v0=0,v1=0,v2=0,v3=0;
  if (idx + 3 < n){ int4v x = *(const int4v*)(src + idx); v0=x[0];v1=x[1];v2=x[2];v3=x[3]; }
  else {
    if (idx   < n) v0 = src[idx];
    if (idx+1 < n) v1 = src[idx+1];
    if (idx+2 < n) v2 = src[idx+2];
    if (idx+3 < n) v3 = src[idx+3];
  }
  int ts = v0+v1+v2+v3;
  int sc = ts;
  for (int d = 1; d < 64; d <<= 1){ int y = __shfl_up(sc, d); if (lane >= d) sc += y; }
  if (lane == 63) wsum[w] = sc;
  __syncthreads();
  int wofs = 0;
  for (int k = 0; k < w; ++k) wofs += wsum[k];
  int base = bpre[blockIdx.x] + wofs + sc - ts;
  int e0 = base, e1 = e0+v0, e2 = e1+v1, e3 = e2+v2;
  if (idx   < n) off[idx  ] = e0;
  if (idx+1 < n) off[idx+1] = e1;
  if (idx+2 < n) off[idx+2] = e2;
  if (idx+3 < n) off[idx+3] = e3;
}

// phase A: scatter edges into per-(bucket,block) exclusive runs (line-exclusive writes)
__global__ void bucket_scatter(const int* __restrict__ eidx, const int* __restrict__ packed,
                               const int* __restrict__ boffT, int* __restrict__ bucketed){
  __shared__ int cur[NBUCK];
  int tid = threadIdx.x, blk = blockIdx.x;
  for (int j = tid; j < NBUCK; j += 512) cur[j] = boffT[j*NBLKA + blk];
  __syncthreads();
  #pragma unroll
  for (int k = 0; k < EB/512; ++k){
    int e = blk*EB + k*512 + tid;
    if (e < N_EDGES){
      int dst = eidx[N_EDGES + e];
      int pos = atomicAdd(&cur[dst >> BSH], 1);
      bucketed[pos] = ((dst & ((1<<BSH)-1)) << 19) | packed[e];
    }
  }
}

// phase B: one block per bucket; LDS cursors from off4; scatter to final CSR positions
__global__ void bucket_sort(const int* __restrict__ bucketed, const int* __restrict__ boffT,
                            const int* __restrict__ off4, int* __restrict__ sorted){
  __shared__ int cur[(1<<BSH)*4];
  int tid = threadIdx.x, b = blockIdx.x;
  int base = b * ((1<<BSH)*4);
  for (int j = tid; j < (1<<BSH)*4; j += 512)
    cur[j] = off4[imin(base + j, SCAN_N)];
  __syncthreads();
  int s = boffT[b*NBLKA];
  int e = boffT[(b+1)*NBLKA];
  for (int i = s + tid; i < e; i += 512){
    int w = bucketed[i];
    int ci = ((w >> 19) << 2) | (w & 3);
    int pos = atomicAdd(&cur[ci], 1);
    sorted[pos] = w & 0x7FFFF;
  }
}

// h_bf16 = bf16(node_feat), stored pi-permuted along d
__global__ void init_h(const float* __restrict__ nf, ushort_t* __restrict__ hB, int n){
  int i = blockIdx.x*256 + threadIdx.x;
  if (i >= n) return;
  int v = i >> 6, pp = (i & 63)*2;
  float f0 = nf[(size_t)v*128 + pinv(pp)];
  float f1 = nf[(size_t)v*128 + pinv(pp+1)];
  *(uint_t*)(hB + (size_t)v*128 + pp) = (uint_t)f2b(f0) | ((uint_t)f2b(f1)<<16);
}

// ---------------- per-step kernels ----------------

// Y(Nx512) = hB(Nx128) @ WY^T  (one-shot; pi-consistent layouts; packed output stores)
__launch_bounds__(512, 2)
__global__ void transform_kernel(const ushort_t* __restrict__ hB, const ushort_t* __restrict__ WY,
                                 ushort_t* __restrict__ Y){
  __shared__ ushort_t lA[128*64];
  __shared__ ushort_t lB[512*64];
  int tid = threadIdx.x, w = tid >> 6, lane = tid & 63;
  int wm = w >> 2, wn = w & 3;
  int row0 = blockIdx.x * 128;
  float4v acc[4][8] = {};
  for (int kt = 0; kt < 2; ++kt){
    short8 va[2], vb[8];
    #pragma unroll
    for (int i = 0; i < 2; ++i){
      int cidx = i*512 + tid;
      int r = cidx >> 3, ch = cidx & 7;
      int node = row0 + r; if (node >= N_NODES) node = N_NODES-1;
      va[i] = *reinterpret_cast<const short8*>(hB + (size_t)node*128 + kt*64 + ch*8);
    }
    #pragma unroll
    for (int i = 0; i < 8; ++i){
      int cidx = i*512 + tid;
      int n = cidx >> 3, ch = cidx & 7;
      vb[i] = *reinterpret_cast<const short8*>(WY + (size_t)n*128 + kt*64 + ch*8);
    }
    __syncthreads();
    #pragma unroll
    for (int i = 0; i < 2; ++i){
      int cidx = i*512 + tid;
      int r = cidx >> 3, ch = cidx & 7;
      *reinterpret_cast<short8*>(lA + r*64 + ((ch ^ (r&7))<<3)) = va[i];
    }
    #pragma unroll
    for (int i = 0; i < 8; ++i){
      int cidx = i*512 + tid;
      int n = cidx >> 3, ch = cidx & 7;
      *reinterpret_cast<short8*>(lB + n*64 + ((ch ^ (n&7))<<3)) = vb[i];
    }
    __syncthreads();
    #pragma unroll
    for (int kk = 0; kk < 2; ++kk){
      int lch = kk*4 + (lane>>4);
      short8 af[4], bf[8];
      #pragma unroll
      for (int i = 0; i < 4; ++i){
        int r = wm*64 + i*16 + (lane&15);
        af[i] = *reinterpret_cast<const short8*>(lA + r*64 + ((lch ^ (r&7))<<3));
      }
      #pragma unroll
      for (int j = 0; j < 8; ++j){
        int n = wn*128 + j*16 + (lane&15);
        bf[j] = *reinterpret_cast<const short8*>(lB + n*64 + ((lch ^ (n&7))<<3));
      }
      #pragma unroll
      for (int i = 0; i < 4; ++i)
        #pragma unroll
        for (int j = 0; j < 8; ++j)
          acc[i][j] = __builtin_amdgcn_mfma_f32_16x16x32_bf16(af[i], bf[j], acc[i][j], 0, 0, 0);
    }
    __syncthreads();
  }
  int l15 = lane & 15;
  #pragma unroll
  for (int i = 0; i < 4; ++i)
    #pragma unroll
    for (int q = 0; q < 4; ++q){
      int grow = row0 + wm*64 + i*16 + (lane>>4)*4 + q;
      if (grow >= N_NODES) continue;
      uint4v u;
      u[0] = cvtpk(acc[i][0][q], acc[i][1][q]);
      u[1] = cvtpk(acc[i][2][q], acc[i][3][q]);
      u[2] = cvtpk(acc[i][4][q], acc[i][5][q]);
      u[3] = cvtpk(acc[i][6][q], acc[i][7][q]);
      *reinterpret_cast<uint4v*>(Y + (size_t)grow*512 + wn*128 + l15*8) = u;
    }
}

// one wave per node: a[v] = sum over in-edges of Y[(src<<2)|t] rows + sum_t cnt*bEp
// (all in pi-space; elementwise sums are permutation-invariant)
__global__ void agg_kernel(const int* __restrict__ off4, const int* __restrict__ sorted,
                           const ushort_t* __restrict__ Y, const int* __restrict__ cnt,
                           const float* __restrict__ bEp, ushort_t* __restrict__ aB){
  int wid = (int)((blockIdx.x * blockDim.x + threadIdx.x) >> 6);
  int lane = threadIdx.x & 63;
  if (wid >= N_NODES) return;
  int s = off4[wid*4], e = off4[wid*4+4];
  int col = lane*2;
  float p0=0,p1=0,q0=0,q1=0,r0=0,r1=0,t0=0,t1=0;
  for (int i = s; i < e; i += 16){
    int vv[16];
    #pragma unroll
    for (int k = 0; k < 16; ++k){
      int j = i + k;
      int sv = sorted[imin(j, e-1)];
      vv[k] = __builtin_amdgcn_readfirstlane(j < e ? sv : ZERO_IDX);
    }
    uint_t hv[16];
    #pragma unroll
    for (int k = 0; k < 16; ++k)
      hv[k] = *(const uint_t*)(Y + (size_t)vv[k]*128 + col);
    #pragma unroll
    for (int k = 0; k < 16; ++k){
      float f0 = bits2f((hv[k] & 0xffffu) << 16);
      float f1 = bits2f(hv[k] & 0xffff0000u);
      if ((k&3)==0){ p0+=f0; p1+=f1; }
      else if ((k&3)==1){ q0+=f0; q1+=f1; }
      else if ((k&3)==2){ r0+=f0; r1+=f1; }
      else { t0+=f0; t1+=f1; }
    }
  }
  float s0 = (p0+q0)+(r0+t0);
  float s1 = (p1+q1)+(r1+t1);
  int4v c4 = *(const int4v*)(cnt + wid*4);
  #pragma unroll
  for (int t = 0; t < 4; ++t){
    float cf = (float)c4[t];
    s0 += cf * bEp[t*128 + col];
    s1 += cf * bEp[t*128 + col + 1];
  }
  *(uint_t*)(aB + (size_t)wid*128 + col) = (uint_t)f2b(s0) | ((uint_t)f2b(s1) << 16);
}

// Fused GRU + next-step transform, v5 (barrier-free MFMA stream):
// Stage BOTH A-tiles (aB[64][128], hB[64][128]) in one prologue -> 1 barrier ->
// all 96 phase-1 MFMAs with B-frags direct from L2, no further barriers.
// Old-h read from resident hB tile. lH stages new-h; 1 barrier; hB/hF write + phase 2.
__launch_bounds__(512, 4)
__global__ void gru_tr_kernel(const ushort_t* __restrict__ aB, ushort_t* __restrict__ hB,
                              const ushort_t* __restrict__ W2f, const ushort_t* __restrict__ WYf,
                              const float* __restrict__ b_ih, const float* __restrict__ b_hh,
                              float* __restrict__ hF, ushort_t* __restrict__ Y, int last){
  __shared__ ushort_t lAB[2][8192];  // [0]=aB tile, [1]=hB tile; [64][128] chunk-XOR swizzled
  __shared__ ushort_t lH[8192];      // [64][128] new-h, same swizzle
  int tid = threadIdx.x, w = tid >> 6, lane = tid & 63;
  int wm = w >> 2, wn = w & 3;       // 2 M x 4 N
  int l15 = lane & 15, lq = lane >> 4;
  int row0 = blockIdx.x * 64;

  // prologue: stage aB + hB tiles (32B per thread per buffer, coalesced)
  {
    int rS = tid >> 3, chS = (tid & 7) * 2;
    int nodeS = imin(row0 + rS, N_NODES-1);
    const short8* ga = reinterpret_cast<const short8*>(aB + (size_t)nodeS*128 + chS*8);
    const short8* gh = reinterpret_cast<const short8*>(hB + (size_t)nodeS*128 + chS*8);
    short8 a0 = ga[0], a1 = ga[1];
    short8 h0 = gh[0], h1 = gh[1];
    int o0 = rS*128 + ((chS ^ (rS&15))<<3);
    int o1 = rS*128 + (((chS+1) ^ (rS&15))<<3);
    *reinterpret_cast<short8*>(&lAB[0][o0]) = a0;
    *reinterpret_cast<short8*>(&lAB[0][o1]) = a1;
    *reinterpret_cast<short8*>(&lAB[1][o0]) = h0;
    *reinterpret_cast<short8*>(&lAB[1][o1]) = h1;
  }
  // hoist bias loads to overlap with staging latency
  int c0 = wn*32 + l15, c1 = c0 + 16;
  float bir0 = b_ih[c0] + b_hh[c0],         bir1 = b_ih[c1] + b_hh[c1];
  float biz0 = b_ih[128+c0] + b_hh[128+c0], biz1 = b_ih[128+c1] + b_hh[128+c1];
  float bni0 = b_ih[256+c0], bni1 = b_ih[256+c1];
  float bnh0 = b_hh[256+c0], bnh1 = b_hh[256+c1];
  __syncthreads();

  float4v acc[2][8] = {};
  #pragma unroll
  for (int kt = 0; kt < 4; ++kt){
    bool lo = (kt < 2);
    const ushort_t* lcur = lAB[kt>>1];
    #pragma unroll
    for (int kk = 0; kk < 2; ++kk){
      int lch = (kt&1)*8 + kk*4 + lq;
      short8 af[2];
      #pragma unroll
      for (int i = 0; i < 2; ++i){
        int r = wm*32 + i*16 + l15;
        af[i] = *reinterpret_cast<const short8*>(lcur + r*128 + ((lch ^ (r&15))<<3));
      }
      #pragma unroll
      for (int j = 0; j < 8; ++j){
        if (lo ? (j >= 6) : (j == 4 || j == 5)) continue;  // known-zero W2 tiles
        int tile = ((wn*8 + j)*4 + kt)*2 + kk;
        short8 bf = *reinterpret_cast<const short8*>(W2f + (size_t)tile*512 + lane*8);
        #pragma unroll
        for (int i = 0; i < 2; ++i)
          acc[i][j] = __builtin_amdgcn_mfma_f32_16x16x32_bf16(af[i], bf, acc[i][j], 0, 0, 0);
      }
    }
  }
  // epilogue: gates in-register, jj-pairs packed; old-h from resident hB tile;
  // new-h -> lH (pi-layout), one cvt_pk + 4B LDS store per (i,q).
  #pragma unroll
  for (int i = 0; i < 2; ++i){
    #pragma unroll
    for (int q = 0; q < 4; ++q){
      int row = wm*32 + i*16 + lq*4 + q;
      uint_t hu = *(const uint_t*)(lAB[1] + row*128 + ((l15 ^ (row&15))<<3) + wn*2);
      float h0 = bits2f((hu & 0xffffu) << 16);
      float h1 = bits2f(hu & 0xffff0000u);
      float rg0 = fsigm(acc[i][0][q] + bir0);
      float zg0 = fsigm(acc[i][2][q] + biz0);
      float nn0 = ftanh(acc[i][4][q] + bni0 + rg0*(acc[i][6][q] + bnh0));
      float out0 = (1.0f - zg0)*nn0 + zg0*h0;
      float rg1 = fsigm(acc[i][1][q] + bir1);
      float zg1 = fsigm(acc[i][3][q] + biz1);
      float nn1 = ftanh(acc[i][5][q] + bni1 + rg1*(acc[i][7][q] + bnh1));
      float out1 = (1.0f - zg1)*nn1 + zg1*h1;
      *(uint_t*)(lH + row*128 + ((l15 ^ (row&15))<<3) + wn*2) = cvtpk(out0, out1);
    }
  }
  __syncthreads();
  // coalesced hB (+hF with pinv if last) from lH: 2 x 16B units per thread
  #pragma unroll
  for (int p = 0; p < 2; ++p){
    int u = p*512 + tid;
    int row = u >> 4, uc = u & 15;
    int grow = row0 + row;
    if (grow < N_NODES){
      short8 v = *reinterpret_cast<const short8*>(lH + row*128 + ((uc ^ (row&15))<<3));
      *reinterpret_cast<short8*>(hB + (size_t)grow*128 + uc*8) = v;
      if (last){
        #pragma unroll
        for (int s = 0; s < 8; ++s)
          hF[(size_t)grow*128 + s*16 + uc] = b2f((ushort_t)v[s]);   // pinv(uc*8+s)=s*16+uc
      }
    }
  }
  if (last) return;
  // phase 2: Y[row0..row0+63][:] = h_new @ WY^T  (A from lH, B fragment-major from L2)
  float4v acc2[2][8] = {};
  #pragma unroll
  for (int kc = 0; kc < 4; ++kc){
    int lchh = kc*4 + lq;
    short8 af[2];
    #pragma unroll
    for (int i = 0; i < 2; ++i){
      int r = wm*32 + i*16 + l15;
      af[i] = *reinterpret_cast<const short8*>(lH + r*128 + ((lchh ^ (r&15))<<3));
    }
    #pragma unroll
    for (int j = 0; j < 8; ++j){
      int tile = (wn*8 + j)*4 + kc;
      short8 bf = *reinterpret_cast<const short8*>(WYf + (size_t)tile*512 + lane*8);
      #pragma unroll
      for (int i = 0; i < 2; ++i)
        acc2[i][j] = __builtin_amdgcn_mfma_f32_16x16x32_bf16(af[i], bf, acc2[i][j], 0, 0, 0);
    }
  }
  #pragma unroll
  for (int i = 0; i < 2; ++i)
    #pragma unroll
    for (int q = 0; q < 4; ++q){
      int grow = row0 + wm*32 + i*16 + lq*4 + q;
      if (grow >= N_NODES) continue;
      uint4v u;
      u[0] = cvtpk(acc2[i][0][q], acc2[i][1][q]);
      u[1] = cvtpk(acc2[i][2][q], acc2[i][3][q]);
      u[2] = cvtpk(acc2[i][4][q], acc2[i][5][q]);
      u[3] = cvtpk(acc2[i][6][q], acc2[i][7][q]);
      *reinterpret_cast<uint4v*>(Y + (size_t)grow*512 + wn*128 + l15*8) = u;
    }
}

// ---------------- launch ----------------

extern "C" void kernel_launch(void* const* d_in, const int* in_sizes, int n_in,
                              void* d_out, int out_size, void* d_ws, size_t ws_size,
                              hipStream_t stream) {
  const float* node_feat = (const float*)d_in[0];
  const int*   edge_idx  = (const int*)d_in[1];
  const float* edge_feat = (const float*)d_in[2];
  const float* W_edge    = (const float*)d_in[3];
  const float* b_edge    = (const float*)d_in[4];
  const float* W_ih      = (const float*)d_in[5];
  const float* W_hh      = (const float*)d_in[6];
  const float* b_ih      = (const float*)d_in[7];
  const float* b_hh      = (const float*)d_in[8];
  float* hF = (float*)d_out;

  char* p = (char*)d_ws;
  auto take = [&](size_t bytes) -> char* {
    char* r = p; p += (bytes + 255) & ~(size_t)255; return r;
  };
  ushort_t* WY     = (ushort_t*)take(512*128*2);
  ushort_t* W2f    = (ushort_t*)take(131072*2);
  ushort_t* WYf    = (ushort_t*)take(65536*2);
  float*    bEp    = (float*)take(512*4);
  int* cnt      = (int*)take((size_t)SCAN_N*4);
  int* off4     = (int*)take((size_t)(SCAN_N+1)*4);
  int* bcntT    = (int*)take((size_t)N2*4);
  int* boffT    = (int*)take((size_t)(N2+1)*4);
  int* bsum     = (int*)take(512*4);
  int* bpre     = (int*)take(512*4);
  int* packed   = (int*)take((size_t)N_EDGES*4);
  int* bucketed = (int*)take((size_t)N_EDGES*4);
  int* sorted   = (int*)take((size_t)N_EDGES*4);
  ushort_t* hB = (ushort_t*)take((size_t)N_NODES*128*2);
  ushort_t* Y  = (ushort_t*)take(((size_t)N_NODES*512 + 256)*2);
  ushort_t* aB = (ushort_t*)take((size_t)N_NODES*128*2);

  hipMemsetAsync(cnt, 0, (size_t)SCAN_N*4, stream);
  hipMemsetAsync(Y + (size_t)N_NODES*512, 0, 256*2, stream);  // zero pad row for agg tail

  prep_weights<<<1028, 256, 0, stream>>>(W_edge, W_ih, W_hh, b_edge, WY, W2f, WYf, bEp);
  edge_pass1<<<NBLKA, 512, 0, stream>>>(edge_idx, edge_feat, packed, cnt, bcntT);
  scan_pass1<<<NB1, 256, 0, stream>>>(cnt, bsum, SCAN_N);
  scan_pass2<<<1, 512, 0, stream>>>(bsum, bpre, off4 + SCAN_N, NB1);
  scan_pass3<<<NB1, 256, 0, stream>>>(cnt, bpre, off4, SCAN_N);
  scan_pass1<<<NB2, 256, 0, stream>>>(bcntT, bsum, N2);
  scan_pass2<<<1, 512, 0, stream>>>(bsum, bpre, boffT + N2, NB2);
  scan_pass3<<<NB2, 256, 0, stream>>>(bcntT, bpre, boffT, N2);
  bucket_scatter<<<NBLKA, 512, 0, stream>>>(edge_idx, packed, boffT, bucketed);
  bucket_sort<<<NBUCK, 512, 0, stream>>>(bucketed, boffT, off4, sorted);
  init_h<<<(N_NODES*64 + 255)/256, 256, 0, stream>>>(node_feat, hB, N_NODES*64);

  int gb = (N_NODES + 127) / 128;    // 782  (one-shot transform)
  int gb2 = (N_NODES + 63) / 64;     // 1563 (fused gru+transform)
  transform_kernel<<<gb, 512, 0, stream>>>(hB, WY, Y);
  for (int step = 0; step < 4; ++step){
    agg_kernel<<<(N_NODES+3)/4, 256, 0, stream>>>(off4, sorted, Y, cnt, bEp, aB);
    gru_tr_kernel<<<gb2, 512, 0, stream>>>(aB, hB, W2f, WYf, b_ih, b_hh, hF, Y, step == 3);
  }
}

// Round 14
// 706.785 us; speedup vs baseline: 1.0440x; 1.0440x over previous
//
#include <hip/hip_runtime.h>

#define N_NODES 100000
#define N_EDGES 1600000
#define HID 128
#define SCAN_N (N_NODES*4)
#define NB1 ((SCAN_N + 1023) / 1024)
#define ZERO_IDX (N_NODES*4)   // gather index of the zero pad row in Y

#define EB 8192                // edges per block in bucket pipeline
#define NBLKA ((N_EDGES + EB - 1) / EB)          // 196
#define BSH 9                  // 512 nodes per bucket
#define NBUCK ((N_NODES + (1<<BSH) - 1) >> BSH)  // 196
#define N2 (NBUCK * NBLKA)
#define NB2 ((N2 + 1023) / 1024)

typedef __attribute__((ext_vector_type(8))) short short8;
typedef __attribute__((ext_vector_type(4))) float float4v;
typedef __attribute__((ext_vector_type(4))) int int4v;
typedef __attribute__((ext_vector_type(4))) unsigned int uint4v;
typedef __attribute__((ext_vector_type(2))) unsigned int uint2v;
typedef unsigned short ushort_t;
typedef unsigned int uint_t;

__device__ __forceinline__ float bits2f(uint_t u){ union{uint_t u; float f;} x; x.u=u; return x.f; }
__device__ __forceinline__ float b2f(ushort_t u){ return bits2f(((uint_t)u)<<16); }
__device__ __forceinline__ ushort_t f2b(float f){
  union{float f; uint_t u;} x; x.f=f;
  uint_t r = x.u + 0x7fffu + ((x.u>>16)&1u);
  return (ushort_t)(r>>16);
}
// packed f32x2 -> bf16x2 (RNE), single instruction
__device__ __forceinline__ uint_t cvtpk(float a, float b){
  uint_t r; asm("v_cvt_pk_bf16_f32 %0, %1, %2" : "=v"(r) : "v"(a), "v"(b)); return r;
}
__device__ __forceinline__ float fsigm(float x){ return __builtin_amdgcn_rcpf(1.0f + __expf(-x)); }
__device__ __forceinline__ float ftanh(float x){ return 2.0f*__builtin_amdgcn_rcpf(1.0f + __expf(-2.0f*x)) - 1.0f; }
__device__ __forceinline__ int imin(int a, int b){ return a < b ? a : b; }
// K-space permutation: stored p = pi(c) = (c&15)*8 + (c>>4); pinv = inverse
__device__ __forceinline__ int pinv(int p){ return ((p&7)<<4) | (p>>3); }

// ---------------- preprocessing ----------------

// All weight K/d indices prepacked with pi applied (storage permutation of the 128-dim).
// WY[g][p] = W_edge[g][pinv(p)], row-major [512][128]  (one-shot transform)
// W2f fragment-major GRU weights, K stored-permuted per 128-half.
// WYf fragment-major W_edge for phase 2, K stored-permuted.
// bEp[t*128+p] = b_edge[t*128+pinv(p)].
__global__ void prep_weights(const float* __restrict__ W_edge, const float* __restrict__ W_ih,
                             const float* __restrict__ W_hh, const float* __restrict__ b_edge,
                             ushort_t* __restrict__ WY, ushort_t* __restrict__ W2f,
                             ushort_t* __restrict__ WYf, float* __restrict__ bEp){
  int i = blockIdx.x*256 + threadIdx.x;
  if (i < 65536){
    int g = i >> 7, p = i & 127;
    WY[i] = f2b(W_edge[g*128 + pinv(p)]);
  } else if (i < 65536 + 131072){
    int i2 = i - 65536;
    int tile = i2 >> 9, e9 = i2 & 511;
    int lane = e9 >> 3, e = e9 & 7;
    int kk = tile & 1, kt = (tile >> 1) & 3, j = (tile >> 3) & 7, wn = tile >> 6;
    int lq = lane >> 4, l15 = lane & 15;
    int c = wn*32 + (j&1)*16 + l15;
    int jg = j >> 1;
    int k = kt*64 + (kk*4 + lq)*8 + e;   // stored K in [0,256)
    int d = pinv(k & 127);               // orig d within the half
    bool aside = (k < 128);
    float v;
    if (jg < 2)       v = aside ? W_ih[(jg*128 + c)*128 + d] : W_hh[(jg*128 + c)*128 + d];
    else if (jg == 2) v = aside ? W_ih[(256 + c)*128 + d] : 0.0f;
    else              v = aside ? 0.0f : W_hh[(256 + c)*128 + d];
    W2f[i2] = f2b(v);
  } else if (i < 65536 + 131072 + 65536){
    int i3 = i - 65536 - 131072;
    int tile = i3 >> 9, e9 = i3 & 511;
    int lane = e9 >> 3, e = e9 & 7;
    int kc = tile & 3, j = (tile >> 2) & 7, wn = tile >> 5;
    int lq = lane >> 4, l15 = lane & 15;
    int n = wn*128 + j*16 + l15;
    int k = kc*32 + lq*8 + e;
    WYf[i3] = f2b(W_edge[n*128 + pinv(k)]);
  } else if (i < 65536 + 131072 + 65536 + 512){
    int i4 = i - 65536 - 131072 - 65536;
    int t = i4 >> 7, p = i4 & 127;
    bEp[i4] = b_edge[t*128 + pinv(p)];
  }
}

// etype argmax, pack (src<<2)|t, histogram cnt[dst*4+t] and per-block bucket hist
__global__ void edge_pass1(const int* __restrict__ eidx, const float* __restrict__ efeat,
                           int* __restrict__ packed, int* __restrict__ cnt,
                           int* __restrict__ bcntT){
  __shared__ int hist[NBUCK];
  int tid = threadIdx.x, blk = blockIdx.x;
  for (int j = tid; j < NBUCK; j += 512) hist[j] = 0;
  __syncthreads();
  #pragma unroll
  for (int k = 0; k < EB/512; ++k){
    int e = blk*EB + k*512 + tid;
    if (e < N_EDGES){
      int src = eidx[e], dst = eidx[N_EDGES + e];
      float4v f = *(const float4v*)(efeat + (size_t)e*4);
      int t = 0; float b = f[0];
      if (f[1] > b){ b = f[1]; t = 1; }
      if (f[2] > b){ b = f[2]; t = 2; }
      if (f[3] > b){ b = f[3]; t = 3; }
      packed[e] = (src << 2) | t;
      atomicAdd(&cnt[dst*4 + t], 1);
      atomicAdd(&hist[dst >> BSH], 1);
    }
  }
  __syncthreads();
  for (int j = tid; j < NBUCK; j += 512) bcntT[j*NBLKA + blk] = hist[j];
}

// generalized 3-pass exclusive scan (n elements)
__global__ void scan_pass1(const int* __restrict__ src, int* __restrict__ bsum, int n){
  __shared__ int ws[4];
  int tid = threadIdx.x, lane = tid & 63, w = tid >> 6;
  int idx = blockIdx.x*1024 + tid*4;
  int v = 0;
  if (idx + 3 < n){ int4v x = *(const int4v*)(src + idx); v = x[0]+x[1]+x[2]+x[3]; }
  else { for (int k = 0; k < 4; ++k) if (idx + k < n) v += src[idx+k]; }
  for (int d = 32; d; d >>= 1) v += __shfl_down(v, d);
  if (lane == 0) ws[w] = v;
  __syncthreads();
  if (tid == 0) bsum[blockIdx.x] = ws[0]+ws[1]+ws[2]+ws[3];
}

__global__ void scan_pass2(const int* __restrict__ bsum, int* __restrict__ bpre,
                           int* __restrict__ total_out, int nb){
  __shared__ int sh[512];
  int tid = threadIdx.x;
  int v = (tid < nb) ? bsum[tid] : 0;
  sh[tid] = v;
  __syncthreads();
  for (int d = 1; d < 512; d <<= 1){
    int y = (tid >= d) ? sh[tid-d] : 0;
    __syncthreads();
    sh[tid] += y;
    __syncthreads();
  }
  if (tid < nb) bpre[tid] = sh[tid] - v;
  if (tid == 511) *total_out = sh[511];
}

__global__ void scan_pass3(const int* __restrict__ src, const int* __restrict__ bpre,
                           int* __restrict__ off, int n){
  __shared__ int wsum[4];
  int tid = threadIdx.x, lane = tid & 63, w = tid >> 6;
  int idx = blockIdx.x*1024 + tid*4;
  int v0=0,v1=0,v2=0,v3=0;
  if (idx + 3 < n){ int4v x = *(const int4v*)(src + idx); v0=x[0];v1=x[1];v2=x[2];v3=x[3]; }
  else {
    if (idx   < n) v0 = src[idx];
    if (idx+1 < n) v1 = src[idx+1];
    if (idx+2 < n) v2 = src[idx+2];
    if (idx+3 < n) v3 = src[idx+3];
  }
  int ts = v0+v1+v2+v3;
  int sc = ts;
  for (int d = 1; d < 64; d <<= 1){ int y = __shfl_up(sc, d); if (lane >= d) sc += y; }
  if (lane == 63) wsum[w] = sc;
  __syncthreads();
  int wofs = 0;
  for (int k = 0; k < w; ++k) wofs += wsum[k];
  int base = bpre[blockIdx.x] + wofs + sc - ts;
  int e0 = base, e1 = e0+v0, e2 = e1+v1, e3 = e2+v2;
  if (idx   < n) off[idx  ] = e0;
  if (idx+1 < n) off[idx+1] = e1;
  if (idx+2 < n) off[idx+2] = e2;
  if (idx+3 < n) off[idx+3] = e3;
}

// phase A: scatter edges into per-(bucket,block) exclusive runs (line-exclusive writes)
__global__ void bucket_scatter(const int* __restrict__ eidx, const int* __restrict__ packed,
                               const int* __restrict__ boffT, int* __restrict__ bucketed){
  __shared__ int cur[NBUCK];
  int tid = threadIdx.x, blk = blockIdx.x;
  for (int j = tid; j < NBUCK; j += 512) cur[j] = boffT[j*NBLKA + blk];
  __syncthreads();
  #pragma unroll
  for (int k = 0; k < EB/512; ++k){
    int e = blk*EB + k*512 + tid;
    if (e < N_EDGES){
      int dst = eidx[N_EDGES + e];
      int pos = atomicAdd(&cur[dst >> BSH], 1);
      bucketed[pos] = ((dst & ((1<<BSH)-1)) << 19) | packed[e];
    }
  }
}

// phase B: one block per bucket; LDS cursors from off4; scatter to final CSR positions
__global__ void bucket_sort(const int* __restrict__ bucketed, const int* __restrict__ boffT,
                            const int* __restrict__ off4, int* __restrict__ sorted){
  __shared__ int cur[(1<<BSH)*4];
  int tid = threadIdx.x, b = blockIdx.x;
  int base = b * ((1<<BSH)*4);
  for (int j = tid; j < (1<<BSH)*4; j += 512)
    cur[j] = off4[imin(base + j, SCAN_N)];
  __syncthreads();
  int s = boffT[b*NBLKA];
  int e = boffT[(b+1)*NBLKA];
  for (int i = s + tid; i < e; i += 512){
    int w = bucketed[i];
    int ci = ((w >> 19) << 2) | (w & 3);
    int pos = atomicAdd(&cur[ci], 1);
    sorted[pos] = w & 0x7FFFF;
  }
}

// h_bf16 = bf16(node_feat), stored pi-permuted along d
__global__ void init_h(const float* __restrict__ nf, ushort_t* __restrict__ hB, int n){
  int i = blockIdx.x*256 + threadIdx.x;
  if (i >= n) return;
  int v = i >> 6, pp = (i & 63)*2;
  float f0 = nf[(size_t)v*128 + pinv(pp)];
  float f1 = nf[(size_t)v*128 + pinv(pp+1)];
  *(uint_t*)(hB + (size_t)v*128 + pp) = (uint_t)f2b(f0) | ((uint_t)f2b(f1)<<16);
}

// ---------------- per-step kernels ----------------

// Y(Nx512) = hB(Nx128) @ WY^T  (one-shot; pi-consistent layouts; packed output stores)
__launch_bounds__(512, 2)
__global__ void transform_kernel(const ushort_t* __restrict__ hB, const ushort_t* __restrict__ WY,
                                 ushort_t* __restrict__ Y){
  __shared__ ushort_t lA[128*64];
  __shared__ ushort_t lB[512*64];
  int tid = threadIdx.x, w = tid >> 6, lane = tid & 63;
  int wm = w >> 2, wn = w & 3;
  int row0 = blockIdx.x * 128;
  float4v acc[4][8] = {};
  for (int kt = 0; kt < 2; ++kt){
    short8 va[2], vb[8];
    #pragma unroll
    for (int i = 0; i < 2; ++i){
      int cidx = i*512 + tid;
      int r = cidx >> 3, ch = cidx & 7;
      int node = row0 + r; if (node >= N_NODES) node = N_NODES-1;
      va[i] = *reinterpret_cast<const short8*>(hB + (size_t)node*128 + kt*64 + ch*8);
    }
    #pragma unroll
    for (int i = 0; i < 8; ++i){
      int cidx = i*512 + tid;
      int n = cidx >> 3, ch = cidx & 7;
      vb[i] = *reinterpret_cast<const short8*>(WY + (size_t)n*128 + kt*64 + ch*8);
    }
    __syncthreads();
    #pragma unroll
    for (int i = 0; i < 2; ++i){
      int cidx = i*512 + tid;
      int r = cidx >> 3, ch = cidx & 7;
      *reinterpret_cast<short8*>(lA + r*64 + ((ch ^ (r&7))<<3)) = va[i];
    }
    #pragma unroll
    for (int i = 0; i < 8; ++i){
      int cidx = i*512 + tid;
      int n = cidx >> 3, ch = cidx & 7;
      *reinterpret_cast<short8*>(lB + n*64 + ((ch ^ (n&7))<<3)) = vb[i];
    }
    __syncthreads();
    #pragma unroll
    for (int kk = 0; kk < 2; ++kk){
      int lch = kk*4 + (lane>>4);
      short8 af[4], bf[8];
      #pragma unroll
      for (int i = 0; i < 4; ++i){
        int r = wm*64 + i*16 + (lane&15);
        af[i] = *reinterpret_cast<const short8*>(lA + r*64 + ((lch ^ (r&7))<<3));
      }
      #pragma unroll
      for (int j = 0; j < 8; ++j){
        int n = wn*128 + j*16 + (lane&15);
        bf[j] = *reinterpret_cast<const short8*>(lB + n*64 + ((lch ^ (n&7))<<3));
      }
      #pragma unroll
      for (int i = 0; i < 4; ++i)
        #pragma unroll
        for (int j = 0; j < 8; ++j)
          acc[i][j] = __builtin_amdgcn_mfma_f32_16x16x32_bf16(af[i], bf[j], acc[i][j], 0, 0, 0);
    }
    __syncthreads();
  }
  int l15 = lane & 15;
  #pragma unroll
  for (int i = 0; i < 4; ++i)
    #pragma unroll
    for (int q = 0; q < 4; ++q){
      int grow = row0 + wm*64 + i*16 + (lane>>4)*4 + q;
      if (grow >= N_NODES) continue;
      uint4v u;
      u[0] = cvtpk(acc[i][0][q], acc[i][1][q]);
      u[1] = cvtpk(acc[i][2][q], acc[i][3][q]);
      u[2] = cvtpk(acc[i][4][q], acc[i][5][q]);
      u[3] = cvtpk(acc[i][6][q], acc[i][7][q]);
      *reinterpret_cast<uint4v*>(Y + (size_t)grow*512 + wn*128 + l15*8) = u;
    }
}

// one wave per node: a[v] = sum over in-edges of Y[(src<<2)|t] rows + sum_t cnt*bEp
// (all in pi-space; elementwise sums are permutation-invariant)
__global__ void agg_kernel(const int* __restrict__ off4, const int* __restrict__ sorted,
                           const ushort_t* __restrict__ Y, const int* __restrict__ cnt,
                           const float* __restrict__ bEp, ushort_t* __restrict__ aB){
  int wid = (int)((blockIdx.x * blockDim.x + threadIdx.x) >> 6);
  int lane = threadIdx.x & 63;
  if (wid >= N_NODES) return;
  int s = off4[wid*4], e = off4[wid*4+4];
  int col = lane*2;
  float p0=0,p1=0,q0=0,q1=0,r0=0,r1=0,t0=0,t1=0;
  for (int i = s; i < e; i += 16){
    int vv[16];
    #pragma unroll
    for (int k = 0; k < 16; ++k){
      int j = i + k;
      int sv = sorted[imin(j, e-1)];
      vv[k] = __builtin_amdgcn_readfirstlane(j < e ? sv : ZERO_IDX);
    }
    uint_t hv[16];
    #pragma unroll
    for (int k = 0; k < 16; ++k)
      hv[k] = *(const uint_t*)(Y + (size_t)vv[k]*128 + col);
    #pragma unroll
    for (int k = 0; k < 16; ++k){
      float f0 = bits2f((hv[k] & 0xffffu) << 16);
      float f1 = bits2f(hv[k] & 0xffff0000u);
      if ((k&3)==0){ p0+=f0; p1+=f1; }
      else if ((k&3)==1){ q0+=f0; q1+=f1; }
      else if ((k&3)==2){ r0+=f0; r1+=f1; }
      else { t0+=f0; t1+=f1; }
    }
  }
  float s0 = (p0+q0)+(r0+t0);
  float s1 = (p1+q1)+(r1+t1);
  int4v c4 = *(const int4v*)(cnt + wid*4);
  #pragma unroll
  for (int t = 0; t < 4; ++t){
    float cf = (float)c4[t];
    s0 += cf * bEp[t*128 + col];
    s1 += cf * bEp[t*128 + col + 1];
  }
  *(uint_t*)(aB + (size_t)wid*128 + col) = (uint_t)f2b(s0) | ((uint_t)f2b(s1) << 16);
}

// Fused GRU + next-step transform, v4 (pi-permuted K-space, packed epilogues):
// 64-row block, 8 waves 2Mx4N, acc[2][8]; launch_bounds(512,4).
// B weights fragment-major from L2; A dbuf in LDS; lH stages new-h (pi-layout).
__launch_bounds__(512, 4)
__global__ void gru_tr_kernel(const ushort_t* __restrict__ aB, ushort_t* __restrict__ hB,
                              const ushort_t* __restrict__ W2f, const ushort_t* __restrict__ WYf,
                              const float* __restrict__ b_ih, const float* __restrict__ b_hh,
                              float* __restrict__ hF, ushort_t* __restrict__ Y, int last){
  __shared__ ushort_t lA[2][4096];   // 2 x [64][64] XOR-swizzled
  __shared__ ushort_t lH[8192];      // [64][128] XOR-swizzled (16 chunks)
  int tid = threadIdx.x, w = tid >> 6, lane = tid & 63;
  int wm = w >> 2, wn = w & 3;       // 2 M x 4 N
  int l15 = lane & 15, lq = lane >> 4;
  int row0 = blockIdx.x * 64;

  int rS = tid >> 3, chS = tid & 7;
  int nodeS = imin(row0 + rS, N_NODES-1);
  size_t aoffS = (size_t)nodeS*128 + chS*8;
  int woS = rS*64 + ((chS ^ (rS&7))<<3);

  *reinterpret_cast<short8*>(&lA[0][woS]) = *reinterpret_cast<const short8*>(aB + aoffS);
  __syncthreads();

  float4v acc[2][8] = {};
  #pragma unroll
  for (int kt = 0; kt < 4; ++kt){
    short8 vn = {};
    if (kt < 3){
      const ushort_t* srcN = (kt+1 < 2) ? aB : hB;
      vn = *reinterpret_cast<const short8*>(srcN + aoffS + ((kt+1)&1)*64);
    }
    bool lo = (kt < 2);
    const ushort_t* lcur = lA[kt&1];
    #pragma unroll
    for (int kk = 0; kk < 2; ++kk){
      int lch = kk*4 + lq;
      short8 af[2];
      #pragma unroll
      for (int i = 0; i < 2; ++i){
        int r = wm*32 + i*16 + l15;
        af[i] = *reinterpret_cast<const short8*>(lcur + r*64 + ((lch ^ (r&7))<<3));
      }
      #pragma unroll
      for (int j = 0; j < 8; ++j){
        if (lo ? (j >= 6) : (j == 4 || j == 5)) continue;  // known-zero W2 tiles
        int tile = ((wn*8 + j)*4 + kt)*2 + kk;
        short8 bf = *reinterpret_cast<const short8*>(W2f + (size_t)tile*512 + lane*8);
        #pragma unroll
        for (int i = 0; i < 2; ++i)
          acc[i][j] = __builtin_amdgcn_mfma_f32_16x16x32_bf16(af[i], bf, acc[i][j], 0, 0, 0);
      }
    }
    if (kt < 3)
      *reinterpret_cast<short8*>(&lA[(kt+1)&1][woS]) = vn;
    __syncthreads();
  }
  // epilogue: gates in-register, jj-pairs packed; old-h from LDS (pi-layout);
  // new-h -> lH (pi-layout), one cvt_pk + 4B LDS store per (i,q).
  {
    int c0 = wn*32 + l15, c1 = c0 + 16;
    float bir0 = b_ih[c0] + b_hh[c0],       bir1 = b_ih[c1] + b_hh[c1];
    float biz0 = b_ih[128+c0] + b_hh[128+c0], biz1 = b_ih[128+c1] + b_hh[128+c1];
    float bni0 = b_ih[256+c0], bni1 = b_ih[256+c1];
    float bnh0 = b_hh[256+c0], bnh1 = b_hh[256+c1];
    int sc = l15*8 + wn*2;                 // stored col (jj adds 0/1); same 8-chunk
    const ushort_t* lhh = lA[sc >> 6];
    int scl = sc & 63;
    #pragma unroll
    for (int i = 0; i < 2; ++i){
      #pragma unroll
      for (int q = 0; q < 4; ++q){
        int row = wm*32 + i*16 + lq*4 + q;
        uint_t hu = *(const uint_t*)(lhh + row*64 + (((scl>>3) ^ (row&7))<<3) + (scl&7));
        float h0 = bits2f((hu & 0xffffu) << 16);
        float h1 = bits2f(hu & 0xffff0000u);
        float rg0 = fsigm(acc[i][0][q] + bir0);
        float zg0 = fsigm(acc[i][2][q] + biz0);
        float nn0 = ftanh(acc[i][4][q] + bni0 + rg0*(acc[i][6][q] + bnh0));
        float out0 = (1.0f - zg0)*nn0 + zg0*h0;
        float rg1 = fsigm(acc[i][1][q] + bir1);
        float zg1 = fsigm(acc[i][3][q] + biz1);
        float nn1 = ftanh(acc[i][5][q] + bni1 + rg1*(acc[i][7][q] + bnh1));
        float out1 = (1.0f - zg1)*nn1 + zg1*h1;
        *(uint_t*)(lH + row*128 + ((l15 ^ (row&15))<<3) + wn*2) = cvtpk(out0, out1);
      }
    }
  }
  __syncthreads();
  // coalesced hB (+hF with pinv if last) from lH: 2 x 16B units per thread
  #pragma unroll
  for (int p = 0; p < 2; ++p){
    int u = p*512 + tid;
    int row = u >> 4, uc = u & 15;
    int grow = row0 + row;
    if (grow < N_NODES){
      short8 v = *reinterpret_cast<const short8*>(lH + row*128 + ((uc ^ (row&15))<<3));
      *reinterpret_cast<short8*>(hB + (size_t)grow*128 + uc*8) = v;
      if (last){
        #pragma unroll
        for (int s = 0; s < 8; ++s)
          hF[(size_t)grow*128 + s*16 + uc] = b2f((ushort_t)v[s]);   // pinv(uc*8+s)=s*16+uc
      }
    }
  }
  if (last) return;
  // phase 2: Y[row0..row0+63][:] = h_new @ WY^T  (A from lH, B fragment-major from L2)
  float4v acc2[2][8] = {};
  #pragma unroll
  for (int kc = 0; kc < 4; ++kc){
    int lchh = kc*4 + lq;
    short8 af[2];
    #pragma unroll
    for (int i = 0; i < 2; ++i){
      int r = wm*32 + i*16 + l15;
      af[i] = *reinterpret_cast<const short8*>(lH + r*128 + ((lchh ^ (r&15))<<3));
    }
    #pragma unroll
    for (int j = 0; j < 8; ++j){
      int tile = (wn*8 + j)*4 + kc;
      short8 bf = *reinterpret_cast<const short8*>(WYf + (size_t)tile*512 + lane*8);
      #pragma unroll
      for (int i = 0; i < 2; ++i)
        acc2[i][j] = __builtin_amdgcn_mfma_f32_16x16x32_bf16(af[i], bf, acc2[i][j], 0, 0, 0);
    }
  }
  #pragma unroll
  for (int i = 0; i < 2; ++i)
    #pragma unroll
    for (int q = 0; q < 4; ++q){
      int grow = row0 + wm*32 + i*16 + lq*4 + q;
      if (grow >= N_NODES) continue;
      uint4v u;
      u[0] = cvtpk(acc2[i][0][q], acc2[i][1][q]);
      u[1] = cvtpk(acc2[i][2][q], acc2[i][3][q]);
      u[2] = cvtpk(acc2[i][4][q], acc2[i][5][q]);
      u[3] = cvtpk(acc2[i][6][q], acc2[i][7][q]);
      *reinterpret_cast<uint4v*>(Y + (size_t)grow*512 + wn*128 + l15*8) = u;
    }
}

// ---------------- launch ----------------

extern "C" void kernel_launch(void* const* d_in, const int* in_sizes, int n_in,
                              void* d_out, int out_size, void* d_ws, size_t ws_size,
                              hipStream_t stream) {
  const float* node_feat = (const float*)d_in[0];
  const int*   edge_idx  = (const int*)d_in[1];
  const float* edge_feat = (const float*)d_in[2];
  const float* W_edge    = (const float*)d_in[3];
  const float* b_edge    = (const float*)d_in[4];
  const float* W_ih      = (const float*)d_in[5];
  const float* W_hh      = (const float*)d_in[6];
  const float* b_ih      = (const float*)d_in[7];
  const float* b_hh      = (const float*)d_in[8];
  float* hF = (float*)d_out;

  char* p = (char*)d_ws;
  auto take = [&](size_t bytes) -> char* {
    char* r = p; p += (bytes + 255) & ~(size_t)255; return r;
  };
  ushort_t* WY     = (ushort_t*)take(512*128*2);
  ushort_t* W2f    = (ushort_t*)take(131072*2);
  ushort_t* WYf    = (ushort_t*)take(65536*2);
  float*    bEp    = (float*)take(512*4);
  int* cnt      = (int*)take((size_t)SCAN_N*4);
  int* off4     = (int*)take((size_t)(SCAN_N+1)*4);
  int* bcntT    = (int*)take((size_t)N2*4);
  int* boffT    = (int*)take((size_t)(N2+1)*4);
  int* bsum     = (int*)take(512*4);
  int* bpre     = (int*)take(512*4);
  int* packed   = (int*)take((size_t)N_EDGES*4);
  int* bucketed = (int*)take((size_t)N_EDGES*4);
  int* sorted   = (int*)take((size_t)N_EDGES*4);
  ushort_t* hB = (ushort_t*)take((size_t)N_NODES*128*2);
  ushort_t* Y  = (ushort_t*)take(((size_t)N_NODES*512 + 256)*2);
  ushort_t* aB = (ushort_t*)take((size_t)N_NODES*128*2);

  hipMemsetAsync(cnt, 0, (size_t)SCAN_N*4, stream);
  hipMemsetAsync(Y + (size_t)N_NODES*512, 0, 256*2, stream);  // zero pad row for agg tail

  prep_weights<<<1028, 256, 0, stream>>>(W_edge, W_ih, W_hh, b_edge, WY, W2f, WYf, bEp);
  edge_pass1<<<NBLKA, 512, 0, stream>>>(edge_idx, edge_feat, packed, cnt, bcntT);
  scan_pass1<<<NB1, 256, 0, stream>>>(cnt, bsum, SCAN_N);
  scan_pass2<<<1, 512, 0, stream>>>(bsum, bpre, off4 + SCAN_N, NB1);
  scan_pass3<<<NB1, 256, 0, stream>>>(cnt, bpre, off4, SCAN_N);
  scan_pass1<<<NB2, 256, 0, stream>>>(bcntT, bsum, N2);
  scan_pass2<<<1, 512, 0, stream>>>(bsum, bpre, boffT + N2, NB2);
  scan_pass3<<<NB2, 256, 0, stream>>>(bcntT, bpre, boffT, N2);
  bucket_scatter<<<NBLKA, 512, 0, stream>>>(edge_idx, packed, boffT, bucketed);
  bucket_sort<<<NBUCK, 512, 0, stream>>>(bucketed, boffT, off4, sorted);
  init_h<<<(N_NODES*64 + 255)/256, 256, 0, stream>>>(node_feat, hB, N_NODES*64);

  int gb = (N_NODES + 127) / 128;    // 782  (one-shot transform)
  int gb2 = (N_NODES + 63) / 64;     // 1563 (fused gru+transform)
  transform_kernel<<<gb, 512, 0, stream>>>(hB, WY, Y);
  for (int step = 0; step < 4; ++step){
    agg_kernel<<<(N_NODES+3)/4, 256, 0, stream>>>(off4, sorted, Y, cnt, bEp, aB);
    gru_tr_kernel<<<gb2, 512, 0, stream>>>(aB, hB, W2f, WYf, b_ih, b_hh, hF, Y, step == 3);
  }
}